// Round 9
// baseline (433.135 us; speedup 1.0000x reference)
//
#include <hip/hip_runtime.h>
#include <math.h>

#define BATCH 4
#define HH 128
#define WWW 128
#define LLEN (HH*WWW)      // 16384
#define CIN 96
#define DI 192
#define KDIR 4
#define NCH 512            // number of chunks
#define PCH 32             // chunk length  (NCH*PCH == LLEN)

// ---------------- Kernel 1: in_proj (1x1 conv, 96 -> 192) ----------------
__global__ __launch_bounds__(256) void k_inproj(const float* __restrict__ x,
                                                const float* __restrict__ w,
                                                float* __restrict__ t0) {
    __shared__ float xin[CIN * 64];     // [c][l] stride 64
    __shared__ float wt[CIN * 65];      // [c][o] stride 65 (pad)
    int bid = blockIdx.x;
    int b = bid >> 8;                   // 256 l-tiles per batch
    int l0 = (bid & 255) << 6;
    int t = threadIdx.x;
    for (int i = 0; i < 24; ++i) {
        int idx = t + i * 256;          // 0..6143
        int c = idx >> 6, l = idx & 63;
        xin[c * 64 + l] = x[((size_t)(b * CIN + c)) * LLEN + l0 + l];
    }
    int o_lane = t & 63;
    int lgrp = t >> 6;                  // 0..3
    for (int ot = 0; ot < 3; ++ot) {
        __syncthreads();
        for (int i = 0; i < 24; ++i) {
            int idx = t + i * 256;      // 0..6143 over (o,c), c fastest
            int o = idx / 96, c = idx - o * 96;
            wt[c * 65 + o] = w[(ot * 64 + o) * 96 + c];
        }
        __syncthreads();
        float4 acc4[4];
        #pragma unroll
        for (int i = 0; i < 4; ++i) acc4[i] = make_float4(0.f, 0.f, 0.f, 0.f);
        int lb = lgrp * 16;
        for (int c = 0; c < CIN; ++c) {
            float wv = wt[c * 65 + o_lane];
            const float4* xv = reinterpret_cast<const float4*>(&xin[c * 64 + lb]);
            #pragma unroll
            for (int i = 0; i < 4; ++i) {
                float4 xx = xv[i];      // broadcast b128
                acc4[i].x += wv * xx.x; acc4[i].y += wv * xx.y;
                acc4[i].z += wv * xx.z; acc4[i].w += wv * xx.w;
            }
        }
        int o = ot * 64 + o_lane;
        #pragma unroll
        for (int i = 0; i < 4; ++i) {
            t0[((size_t)(b * LLEN) + l0 + lb + i * 4 + 0) * DI + o] = acc4[i].x;
            t0[((size_t)(b * LLEN) + l0 + lb + i * 4 + 1) * DI + o] = acc4[i].y;
            t0[((size_t)(b * LLEN) + l0 + lb + i * 4 + 2) * DI + o] = acc4[i].z;
            t0[((size_t)(b * LLEN) + l0 + lb + i * 4 + 3) * DI + o] = acc4[i].w;
        }
    }
}

// ------------- Kernel 2: depthwise 3x3 conv + bias + SiLU ---------------
__global__ __launch_bounds__(192) void k_dwconv(const float* __restrict__ t0,
                                                const float* __restrict__ cw,
                                                const float* __restrict__ cb,
                                                float* __restrict__ xf) {
    int bid = blockIdx.x;
    int wt = (bid & 15) << 3;           // 16 tiles of 8 along w
    int h  = (bid >> 4) & (HH - 1);
    int b  = bid >> 11;
    int d  = threadIdx.x;
    float acc[8];
    float bias = cb[d];
    #pragma unroll
    for (int j = 0; j < 8; ++j) acc[j] = bias;
    #pragma unroll
    for (int kh = 0; kh < 3; ++kh) {
        int hh = h + kh - 1;
        if (hh < 0 || hh >= HH) continue;
        float w0v = cw[d * 9 + kh * 3 + 0];
        float w1v = cw[d * 9 + kh * 3 + 1];
        float w2v = cw[d * 9 + kh * 3 + 2];
        const float* rowp = t0 + ((size_t)(b * LLEN) + hh * WWW) * DI + d;
        float v[10];
        #pragma unroll
        for (int j = 0; j < 10; ++j) {
            int ww = wt + j - 1;
            v[j] = (ww < 0 || ww >= WWW) ? 0.f : rowp[(size_t)ww * DI];
        }
        #pragma unroll
        for (int j = 0; j < 8; ++j)
            acc[j] += w0v * v[j] + w1v * v[j + 1] + w2v * v[j + 2];
    }
    size_t outbase = ((size_t)(b * LLEN) + h * WWW + wt) * DI + d;
    #pragma unroll
    for (int j = 0; j < 8; ++j) {
        float aa = acc[j];
        float s = aa * __builtin_amdgcn_rcpf(1.f + __expf(-aa));  // fast SiLU
        xf[outbase + (size_t)j * DI] = s;
    }
}

// ---- Kernel 3: x_proj for ALL 4 directions in NATURAL order ------------
// xdblp[b*L + l][32] = dot(xf[b,l,:], xpw[k,c,:]) for ch = k*8+c.
// Permutation-independent: computed once, gathered later by the scans.
__global__ __launch_bounds__(256) void k_proj(const float* __restrict__ xf,
                                              const float* __restrict__ xpw,
                                              float* __restrict__ xdblp) {
    __shared__ float wl[32 * DI];       // 24.6 KB [ch][d]
    __shared__ float part[4 * 32 * 33]; // 16.9 KB [wq][p][ch] stride 33
    int bid = blockIdx.x;               // 0..2047 over (B*L)/32
    int t = threadIdx.x;
    // stage all weights (6144 floats = 1536 float4, 6/thread, coalesced)
    {
        const float4* wsrc = reinterpret_cast<const float4*>(xpw);
        float4* wdst = reinterpret_cast<float4*>(wl);
        #pragma unroll
        for (int i = 0; i < 6; ++i) wdst[t + i * 256] = wsrc[t + i * 256];
    }
    int p = t & 31, s = t >> 5;         // 32 positions x 8 segments
    const float4* row = reinterpret_cast<const float4*>(
        xf + ((size_t)bid * 32 + p) * DI + s * 24);
    float4 v[6];
    #pragma unroll
    for (int j = 0; j < 6; ++j) v[j] = row[j];
    __syncthreads();
    float pd[32];
    #pragma unroll
    for (int ch = 0; ch < 32; ++ch) {
        const float4* w4 = reinterpret_cast<const float4*>(wl + ch * DI + s * 24);
        float a0 = 0.f;
        #pragma unroll
        for (int j = 0; j < 6; ++j) {
            float4 wv = w4[j];
            a0 += wv.x * v[j].x + wv.y * v[j].y + wv.z * v[j].z + wv.w * v[j].w;
        }
        pd[ch] = a0;
    }
    #pragma unroll
    for (int ch = 0; ch < 32; ++ch) pd[ch] += __shfl_xor(pd[ch], 32);
    if ((s & 1) == 0) {
        int wq = s >> 1;                // 0..3
        #pragma unroll
        for (int ch = 0; ch < 32; ++ch) part[(wq * 32 + p) * 33 + ch] = pd[ch];
    }
    __syncthreads();
    // final reduce + coalesced store: thread t -> pos=t>>3, c4=t&7
    int pos = t >> 3, c4 = t & 7;
    float r[4];
    #pragma unroll
    for (int i = 0; i < 4; ++i) {
        int ch = c4 * 4 + i;
        r[i] = part[pos * 33 + ch] + part[(32 + pos) * 33 + ch] +
               part[(64 + pos) * 33 + ch] + part[(96 + pos) * 33 + ch];
    }
    reinterpret_cast<float4*>(xdblp + (size_t)bid * 1024)[t] =
        make_float4(r[0], r[1], r[2], r[3]);
}

// ---- Kernel 4: phase-1 lite — gather proj + u, chunk summary -----------
__global__ __launch_bounds__(192) void k_scan1(const float* __restrict__ xf,
                                               const int* __restrict__ sids,
                                               const float* __restrict__ xdblp,
                                               const float* __restrict__ dtw,
                                               const float* __restrict__ dtb,
                                               const float* __restrict__ alog,
                                               float* __restrict__ cA,
                                               float* __restrict__ cB) {
    __shared__ float xdbl[PCH * 8];
    __shared__ int sid[PCH];
    int bid = blockIdx.x;
    int c = bid & (NCH - 1);
    int k = (bid >> 9) & 3;
    int b = bid >> 11;
    int t = threadIdx.x;
    if (t < PCH) sid[t] = sids[k * LLEN + c * PCH + t];
    __syncthreads();
    if (t < 64) {
        int p = t >> 1, half = t & 1;
        reinterpret_cast<float4*>(xdbl)[t] = *reinterpret_cast<const float4*>(
            xdblp + ((size_t)(b * LLEN) + sid[p]) * 32 + k * 8 + half * 4);
    }
    __syncthreads();
    int d = t;
    const float* ubase = xf + (size_t)(b * LLEN) * DI + d;
    float uv[PCH];
    #pragma unroll
    for (int p = 0; p < PCH; ++p) uv[p] = ubase[(size_t)sid[p] * DI];
    float wr[6];
    #pragma unroll
    for (int r = 0; r < 6; ++r) wr[r] = dtw[(k * DI + d) * 6 + r];
    float bias = dtb[k * DI + d];
    float A = -__expf(alog[k * DI + d]);
    float Ar = 1.f, Br = 0.f;
    const float4* xd4 = reinterpret_cast<const float4*>(xdbl);
    #pragma unroll
    for (int p = 0; p < PCH; ++p) {
        float4 x0 = xd4[p * 2], x1 = xd4[p * 2 + 1];
        float s = bias + wr[0] * x0.x + wr[1] * x0.y + wr[2] * x0.z +
                  wr[3] * x0.w + wr[4] * x1.x + wr[5] * x1.y;
        float delta = (s > 20.f) ? s : __logf(1.f + __expf(s));
        float a = __expf(delta * A);
        float bu = delta * x1.z * uv[p];
        Br = a * Br + bu;
        Ar *= a;
    }
    cA[(size_t)bid * DI + d] = Ar;
    cB[(size_t)bid * DI + d] = Br;
}

// ---- chunk-summary scans (3 tiny kernels; NSEG=16 segs of 32 chunks) ----
__global__ __launch_bounds__(192) void k_cs1(const float* __restrict__ cA,
                                             const float* __restrict__ cB,
                                             float* __restrict__ segA,
                                             float* __restrict__ segB) {
    int g = blockIdx.x;                 // bk*16 + seg
    int d = threadIdx.x;
    size_t base = (size_t)g * 32 * DI + d;
    float A = 1.f, Bv = 0.f;
    for (int cc = 0; cc < 32; ++cc) {
        float a = cA[base + (size_t)cc * DI];
        float bb = cB[base + (size_t)cc * DI];
        Bv = a * Bv + bb;
        A *= a;
    }
    segA[(size_t)g * DI + d] = A;
    segB[(size_t)g * DI + d] = Bv;
}
__global__ __launch_bounds__(192) void k_cs2(const float* __restrict__ segA,
                                             const float* __restrict__ segB,
                                             float* __restrict__ hseg) {
    int bk = blockIdx.x;                // 0..15
    int d = threadIdx.x;
    float h = 0.f;
    for (int seg = 0; seg < 16; ++seg) {
        size_t idx = (size_t)(bk * 16 + seg) * DI + d;
        hseg[idx] = h;
        h = segA[idx] * h + segB[idx];
    }
}
__global__ __launch_bounds__(192) void k_cs3(const float* __restrict__ cA,
                                             float* __restrict__ cB,
                                             const float* __restrict__ hseg) {
    int g = blockIdx.x;                 // bk*16 + seg
    int d = threadIdx.x;
    float h = hseg[(size_t)g * DI + d];
    size_t base = (size_t)g * 32 * DI + d;
    for (int cc = 0; cc < 32; ++cc) {
        size_t ix = base + (size_t)cc * DI;
        float a = cA[ix];
        float bb = cB[ix];
        cB[ix] = h;                     // hin for this chunk
        h = a * h + bb;
    }
}

// ---- Kernel 5: phase-3 — scan replay + NON-ATOMIC scatter --------------
template <bool ACCUM>
__global__ __launch_bounds__(192) void k_scan3(const float* __restrict__ xf,
                                               const int* __restrict__ sids,
                                               const float* __restrict__ dtw,
                                               const float* __restrict__ dtb,
                                               const float* __restrict__ alog,
                                               const float* __restrict__ dsv,
                                               const float* __restrict__ hin,
                                               const float* __restrict__ xdblp,
                                               float* __restrict__ y,
                                               int k) {
    __shared__ float xdbl[PCH * 8];
    __shared__ int sid[PCH];
    int bid = blockIdx.x;               // b*NCH + c
    int c = bid & (NCH - 1);
    int b = bid >> 9;
    int t = threadIdx.x;
    size_t gidx = (size_t)((b * KDIR + k) * NCH + c);
    if (t < PCH) sid[t] = sids[k * LLEN + c * PCH + t];
    __syncthreads();
    if (t < 64) {
        int p = t >> 1, half = t & 1;
        reinterpret_cast<float4*>(xdbl)[t] = *reinterpret_cast<const float4*>(
            xdblp + ((size_t)(b * LLEN) + sid[p]) * 32 + k * 8 + half * 4);
    }
    __syncthreads();
    int d = t;
    const float* ubase = xf + (size_t)(b * LLEN) * DI + d;
    float* ybase = y + (size_t)(b * LLEN) * DI + d;
    float uv[PCH];
    #pragma unroll
    for (int p = 0; p < PCH; ++p) uv[p] = ubase[(size_t)sid[p] * DI];
    float yv[PCH];
    if (ACCUM) {
        #pragma unroll
        for (int p = 0; p < PCH; ++p) yv[p] = ybase[(size_t)sid[p] * DI];
    }
    float wr[6];
    #pragma unroll
    for (int r = 0; r < 6; ++r) wr[r] = dtw[(k * DI + d) * 6 + r];
    float bias = dtb[k * DI + d];
    float A = -__expf(alog[k * DI + d]);
    float Dv = dsv[k * DI + d];
    float h = hin[gidx * DI + d];
    const float4* xd4 = reinterpret_cast<const float4*>(xdbl);
    #pragma unroll
    for (int p = 0; p < PCH; ++p) {
        float4 x0 = xd4[p * 2], x1 = xd4[p * 2 + 1];
        float s = bias + wr[0] * x0.x + wr[1] * x0.y + wr[2] * x0.z +
                  wr[3] * x0.w + wr[4] * x1.x + wr[5] * x1.y;
        float delta = (s > 20.f) ? s : __logf(1.f + __expf(s));
        float a = __expf(delta * A);
        float bu = delta * x1.z * uv[p];
        h = a * h + bu;
        float ys = x1.w * h + Dv * uv[p];
        if (ACCUM) ys += yv[p];
        ybase[(size_t)sid[p] * DI] = ys;    // plain store, no atomic
    }
}

// ------------- Kernel 6: GELU + out_proj (192 -> 96) --------------------
__global__ __launch_bounds__(256) void k_out(const float* __restrict__ y,
                                             const float* __restrict__ wo,
                                             float* __restrict__ out) {
    __shared__ float gy[DI * 65];       // [c][l] stride 65 (pad)
    int bid = blockIdx.x;
    int b = bid >> 8;
    int l0 = (bid & 255) << 6;
    int t = threadIdx.x;
    for (int i = 0; i < 48; ++i) {
        int idx = t + i * 256;          // 0..12287
        int l = idx / DI;
        int cc = idx - l * DI;
        float v = y[((size_t)(b * LLEN) + l0 + l) * DI + cc];
        float z = 0.7978845608028654f * (v + 0.044715f * v * v * v);
        float e = __expf(2.f * z);
        float th = 1.f - 2.f * __builtin_amdgcn_rcpf(e + 1.f);
        gy[cc * 65 + l] = 0.5f * v * (1.f + th);
    }
    __syncthreads();
    int lq = t & 15, oh = t >> 4;
    float acc[6][4];
    #pragma unroll
    for (int i = 0; i < 6; ++i)
        #pragma unroll
        for (int e = 0; e < 4; ++e) acc[i][e] = 0.f;
    for (int cc = 0; cc < DI; cc += 4) {
        float4 wv[6];
        #pragma unroll
        for (int i = 0; i < 6; ++i)
            wv[i] = *reinterpret_cast<const float4*>(&wo[(oh * 6 + i) * DI + cc]);
        float g[4][4];                  // [e_l][e_cc]
        #pragma unroll
        for (int el = 0; el < 4; ++el) {
            g[el][0] = gy[(cc + 0) * 65 + lq * 4 + el];
            g[el][1] = gy[(cc + 1) * 65 + lq * 4 + el];
            g[el][2] = gy[(cc + 2) * 65 + lq * 4 + el];
            g[el][3] = gy[(cc + 3) * 65 + lq * 4 + el];
        }
        #pragma unroll
        for (int i = 0; i < 6; ++i)
            #pragma unroll
            for (int el = 0; el < 4; ++el)
                acc[i][el] += wv[i].x * g[el][0] + wv[i].y * g[el][1] +
                              wv[i].z * g[el][2] + wv[i].w * g[el][3];
    }
    #pragma unroll
    for (int i = 0; i < 6; ++i) {
        int o = oh * 6 + i;
        float4 st = make_float4(acc[i][0], acc[i][1], acc[i][2], acc[i][3]);
        *reinterpret_cast<float4*>(&out[((size_t)(b * CIN) + o) * LLEN + l0 + lq * 4]) = st;
    }
}

extern "C" void kernel_launch(void* const* d_in, const int* in_sizes, int n_in,
                              void* d_out, int out_size, void* d_ws, size_t ws_size,
                              hipStream_t stream) {
    const float* x        = (const float*)d_in[0];
    const int*   scan_ids = (const int*)d_in[1];
    const float* in_proj_w = (const float*)d_in[3];
    const float* conv_w    = (const float*)d_in[4];
    const float* conv_b    = (const float*)d_in[5];
    const float* xpw       = (const float*)d_in[6];
    const float* dtw       = (const float*)d_in[7];
    const float* dtb       = (const float*)d_in[8];
    const float* alog      = (const float*)d_in[9];
    const float* dsv       = (const float*)d_in[10];
    const float* wo        = (const float*)d_in[11];
    float* out = (float*)d_out;

    float* ws = (float*)d_ws;
    const size_t NBL  = (size_t)BATCH * LLEN * DI;        // 12.58M floats
    const size_t NCK  = (size_t)BATCH * KDIR * NCH * DI;  // 1.57M floats
    const size_t NXD  = (size_t)BATCH * LLEN * 32;        // 2.10M floats
    const size_t NSG  = (size_t)BATCH * KDIR * 16 * DI;   // 49152 floats
    float* t0    = ws;             // in_proj out; later reused as y
    float* xf    = t0 + NBL;
    float* xdblp = xf + NBL;
    float* cA    = xdblp + NXD;
    float* cB    = cA + NCK;       // becomes hin after k_cs3
    float* segA  = cB + NCK;
    float* segB  = segA + NSG;
    float* hseg  = segB + NSG;
    float* y     = t0;

    k_inproj<<<BATCH * 256, 256, 0, stream>>>(x, in_proj_w, t0);
    k_dwconv<<<BATCH * HH * 16, 192, 0, stream>>>(t0, conv_w, conv_b, xf);
    k_proj<<<(BATCH * LLEN) / 32, 256, 0, stream>>>(xf, xpw, xdblp);
    k_scan1<<<BATCH * KDIR * NCH, 192, 0, stream>>>(xf, scan_ids, xdblp, dtw, dtb,
                                                    alog, cA, cB);
    k_cs1<<<BATCH * KDIR * 16, 192, 0, stream>>>(cA, cB, segA, segB);
    k_cs2<<<BATCH * KDIR, 192, 0, stream>>>(segA, segB, hseg);
    k_cs3<<<BATCH * KDIR * 16, 192, 0, stream>>>(cA, cB, hseg);
    k_scan3<false><<<BATCH * NCH, 192, 0, stream>>>(xf, scan_ids, dtw, dtb,
                                                    alog, dsv, cB, xdblp, y, 0);
    for (int k = 1; k < KDIR; ++k)
        k_scan3<true><<<BATCH * NCH, 192, 0, stream>>>(xf, scan_ids, dtw, dtb,
                                                       alog, dsv, cB, xdblp, y, k);
    k_out<<<BATCH * 256, 256, 0, stream>>>(y, wo, out);
}

// Round 11
// 384.336 us; speedup vs baseline: 1.1270x; 1.1270x over previous
//
#include <hip/hip_runtime.h>
#include <math.h>

#define BATCH 4
#define HH 128
#define WWW 128
#define LLEN (HH*WWW)      // 16384
#define CIN 96
#define DI 192
#define KDIR 4
#define NCH 512            // number of chunks
#define PCH 32             // chunk length  (NCH*PCH == LLEN)

typedef __attribute__((ext_vector_type(8))) short bf16x8;
typedef __attribute__((ext_vector_type(4))) float floatx4;

__device__ inline unsigned pack_bf16(float a, float b) {
    unsigned ua = __float_as_uint(a); ua = (ua + 0x7fffu + ((ua >> 16) & 1u)) >> 16;
    unsigned ub = __float_as_uint(b); ub = (ub + 0x7fffu + ((ub >> 16) & 1u)) >> 16;
    return ua | (ub << 16);
}

// ---------------- w (192x96) fp32 -> bf16 (same layout) -----------------
__global__ __launch_bounds__(256) void k_cvtw(const float* __restrict__ w,
                                              unsigned* __restrict__ wb) {
    int i = blockIdx.x * 256 + threadIdx.x;   // 9216 threads, 2 elems each
    float2 v = reinterpret_cast<const float2*>(w)[i];
    wb[i] = pack_bf16(v.x, v.y);
}

// ------- x (B,96,L) fp32 -> Xb (B,L,96) bf16 (transposed copy) ----------
__global__ __launch_bounds__(256) void k_cvt(const float* __restrict__ x,
                                             unsigned short* __restrict__ xb) {
    int g = blockIdx.x * 256 + threadIdx.x;   // 65536 threads = b*L + l
    int b = g >> 14, l = g & (LLEN - 1);
    const float* xp = x + (size_t)b * CIN * LLEN + l;
    uint4* dst = reinterpret_cast<uint4*>(xb + (size_t)g * CIN);
    #pragma unroll
    for (int c0 = 0; c0 < CIN; c0 += 8) {
        float v[8];
        #pragma unroll
        for (int j = 0; j < 8; ++j) v[j] = xp[(size_t)(c0 + j) * LLEN];
        uint4 o;
        o.x = pack_bf16(v[0], v[1]); o.y = pack_bf16(v[2], v[3]);
        o.z = pack_bf16(v[4], v[5]); o.w = pack_bf16(v[6], v[7]);
        dst[c0 >> 3] = o;
    }
}

// ---------- Kernel 1: in_proj via MFMA (bf16 in, fp32 out) --------------
// t0[b,l,o] = sum_c Xb[b,l,c] * Wb[o,c].  M->l, N->o, K=96 (3 x 32).
// A-frag: lane holds Xb[l0 + (lane&15)][kg*8 .. +8)  (16B contiguous)
// B-frag: lane holds Wb[o0 + (lane&15)][kg*8 .. +8)  (16B contiguous)
// D: col(o) = lane&15, row(l) = kg*4 + reg.
__global__ __launch_bounds__(256) void k_inproj(const unsigned short* __restrict__ xb,
                                                const unsigned short* __restrict__ wb,
                                                float* __restrict__ t0) {
    int bid = blockIdx.x;               // 1024: b*256 + ltile
    int t = threadIdx.x;
    int wv = t >> 6, lane = t & 63;
    int b = bid >> 8;
    int l0 = (bid & 255) * 64 + wv * 16;
    int m = lane & 15, kg = lane >> 4;
    const unsigned short* xrow = xb + ((size_t)(b * LLEN) + l0 + m) * CIN + kg * 8;
    bf16x8 a0 = *reinterpret_cast<const bf16x8*>(xrow);
    bf16x8 a1 = *reinterpret_cast<const bf16x8*>(xrow + 32);
    bf16x8 a2 = *reinterpret_cast<const bf16x8*>(xrow + 64);
    float* obase = t0 + ((size_t)(b * LLEN) + l0 + kg * 4) * DI + m;
    #pragma unroll
    for (int ot = 0; ot < 12; ++ot) {
        const unsigned short* wrow = wb + (size_t)(ot * 16 + m) * CIN + kg * 8;
        bf16x8 b0 = *reinterpret_cast<const bf16x8*>(wrow);
        bf16x8 b1 = *reinterpret_cast<const bf16x8*>(wrow + 32);
        bf16x8 b2 = *reinterpret_cast<const bf16x8*>(wrow + 64);
        floatx4 acc = {0.f, 0.f, 0.f, 0.f};
        acc = __builtin_amdgcn_mfma_f32_16x16x32_bf16(a0, b0, acc, 0, 0, 0);
        acc = __builtin_amdgcn_mfma_f32_16x16x32_bf16(a1, b1, acc, 0, 0, 0);
        acc = __builtin_amdgcn_mfma_f32_16x16x32_bf16(a2, b2, acc, 0, 0, 0);
        #pragma unroll
        for (int r = 0; r < 4; ++r)
            obase[(size_t)r * DI + ot * 16] = acc[r];
    }
}

// ------------- Kernel 2: depthwise 3x3 conv + bias + SiLU ---------------
__global__ __launch_bounds__(192) void k_dwconv(const float* __restrict__ t0,
                                                const float* __restrict__ cw,
                                                const float* __restrict__ cb,
                                                float* __restrict__ xf) {
    int bid = blockIdx.x;
    int wt = (bid & 15) << 3;           // 16 tiles of 8 along w
    int h  = (bid >> 4) & (HH - 1);
    int b  = bid >> 11;
    int d  = threadIdx.x;
    float acc[8];
    float bias = cb[d];
    #pragma unroll
    for (int j = 0; j < 8; ++j) acc[j] = bias;
    #pragma unroll
    for (int kh = 0; kh < 3; ++kh) {
        int hh = h + kh - 1;
        if (hh < 0 || hh >= HH) continue;
        float w0v = cw[d * 9 + kh * 3 + 0];
        float w1v = cw[d * 9 + kh * 3 + 1];
        float w2v = cw[d * 9 + kh * 3 + 2];
        const float* rowp = t0 + ((size_t)(b * LLEN) + hh * WWW) * DI + d;
        float v[10];
        #pragma unroll
        for (int j = 0; j < 10; ++j) {
            int ww = wt + j - 1;
            v[j] = (ww < 0 || ww >= WWW) ? 0.f : rowp[(size_t)ww * DI];
        }
        #pragma unroll
        for (int j = 0; j < 8; ++j)
            acc[j] += w0v * v[j] + w1v * v[j + 1] + w2v * v[j + 2];
    }
    size_t outbase = ((size_t)(b * LLEN) + h * WWW + wt) * DI + d;
    #pragma unroll
    for (int j = 0; j < 8; ++j) {
        float aa = acc[j];
        float s = aa * __builtin_amdgcn_rcpf(1.f + __expf(-aa));  // fast SiLU
        xf[outbase + (size_t)j * DI] = s;
    }
}

// ---- Kernel 3: x_proj for ALL 4 directions in NATURAL order ------------
__global__ __launch_bounds__(256) void k_proj(const float* __restrict__ xf,
                                              const float* __restrict__ xpw,
                                              float* __restrict__ xdblp) {
    __shared__ float wl[32 * DI];       // 24.6 KB [ch][d]
    __shared__ float part[4 * 32 * 33]; // 16.9 KB [wq][p][ch] stride 33
    int bid = blockIdx.x;               // 0..2047 over (B*L)/32
    int t = threadIdx.x;
    {
        const float4* wsrc = reinterpret_cast<const float4*>(xpw);
        float4* wdst = reinterpret_cast<float4*>(wl);
        #pragma unroll
        for (int i = 0; i < 6; ++i) wdst[t + i * 256] = wsrc[t + i * 256];
    }
    int p = t & 31, s = t >> 5;         // 32 positions x 8 segments
    const float4* row = reinterpret_cast<const float4*>(
        xf + ((size_t)bid * 32 + p) * DI + s * 24);
    float4 v[6];
    #pragma unroll
    for (int j = 0; j < 6; ++j) v[j] = row[j];
    __syncthreads();
    float pd[32];
    #pragma unroll
    for (int ch = 0; ch < 32; ++ch) {
        const float4* w4 = reinterpret_cast<const float4*>(wl + ch * DI + s * 24);
        float a0 = 0.f;
        #pragma unroll
        for (int j = 0; j < 6; ++j) {
            float4 wv = w4[j];
            a0 += wv.x * v[j].x + wv.y * v[j].y + wv.z * v[j].z + wv.w * v[j].w;
        }
        pd[ch] = a0;
    }
    #pragma unroll
    for (int ch = 0; ch < 32; ++ch) pd[ch] += __shfl_xor(pd[ch], 32);
    if ((s & 1) == 0) {
        int wq = s >> 1;                // 0..3
        #pragma unroll
        for (int ch = 0; ch < 32; ++ch) part[(wq * 32 + p) * 33 + ch] = pd[ch];
    }
    __syncthreads();
    int pos = t >> 3, c4 = t & 7;
    float r[4];
    #pragma unroll
    for (int i = 0; i < 4; ++i) {
        int ch = c4 * 4 + i;
        r[i] = part[pos * 33 + ch] + part[(32 + pos) * 33 + ch] +
               part[(64 + pos) * 33 + ch] + part[(96 + pos) * 33 + ch];
    }
    reinterpret_cast<float4*>(xdblp + (size_t)bid * 1024)[t] =
        make_float4(r[0], r[1], r[2], r[3]);
}

// ---- Kernel 4: phase-1 lite — gather proj + u, chunk summary -----------
__global__ __launch_bounds__(192) void k_scan1(const float* __restrict__ xf,
                                               const int* __restrict__ sids,
                                               const float* __restrict__ xdblp,
                                               const float* __restrict__ dtw,
                                               const float* __restrict__ dtb,
                                               const float* __restrict__ alog,
                                               float* __restrict__ cA,
                                               float* __restrict__ cB) {
    __shared__ float xdbl[PCH * 8];
    __shared__ int sid[PCH];
    int bid = blockIdx.x;
    int c = bid & (NCH - 1);
    int k = (bid >> 9) & 3;
    int b = bid >> 11;
    int t = threadIdx.x;
    if (t < PCH) sid[t] = sids[k * LLEN + c * PCH + t];
    __syncthreads();
    if (t < 64) {
        int p = t >> 1, half = t & 1;
        reinterpret_cast<float4*>(xdbl)[t] = *reinterpret_cast<const float4*>(
            xdblp + ((size_t)(b * LLEN) + sid[p]) * 32 + k * 8 + half * 4);
    }
    __syncthreads();
    int d = t;
    const float* ubase = xf + (size_t)(b * LLEN) * DI + d;
    float uv[PCH];
    #pragma unroll
    for (int p = 0; p < PCH; ++p) uv[p] = ubase[(size_t)sid[p] * DI];
    float wr[6];
    #pragma unroll
    for (int r = 0; r < 6; ++r) wr[r] = dtw[(k * DI + d) * 6 + r];
    float bias = dtb[k * DI + d];
    float A = -__expf(alog[k * DI + d]);
    float Ar = 1.f, Br = 0.f;
    const float4* xd4 = reinterpret_cast<const float4*>(xdbl);
    #pragma unroll
    for (int p = 0; p < PCH; ++p) {
        float4 x0 = xd4[p * 2], x1 = xd4[p * 2 + 1];
        float s = bias + wr[0] * x0.x + wr[1] * x0.y + wr[2] * x0.z +
                  wr[3] * x0.w + wr[4] * x1.x + wr[5] * x1.y;
        float delta = (s > 20.f) ? s : __logf(1.f + __expf(s));
        float a = __expf(delta * A);
        float bu = delta * x1.z * uv[p];
        Br = a * Br + bu;
        Ar *= a;
    }
    cA[(size_t)bid * DI + d] = Ar;
    cB[(size_t)bid * DI + d] = Br;
}

// ---- chunk-summary scans (3 tiny kernels; NSEG=16 segs of 32 chunks) ----
__global__ __launch_bounds__(192) void k_cs1(const float* __restrict__ cA,
                                             const float* __restrict__ cB,
                                             float* __restrict__ segA,
                                             float* __restrict__ segB) {
    int g = blockIdx.x;                 // bk*16 + seg
    int d = threadIdx.x;
    size_t base = (size_t)g * 32 * DI + d;
    float A = 1.f, Bv = 0.f;
    for (int cc = 0; cc < 32; ++cc) {
        float a = cA[base + (size_t)cc * DI];
        float bb = cB[base + (size_t)cc * DI];
        Bv = a * Bv + bb;
        A *= a;
    }
    segA[(size_t)g * DI + d] = A;
    segB[(size_t)g * DI + d] = Bv;
}
__global__ __launch_bounds__(192) void k_cs2(const float* __restrict__ segA,
                                             const float* __restrict__ segB,
                                             float* __restrict__ hseg) {
    int bk = blockIdx.x;                // 0..15
    int d = threadIdx.x;
    float h = 0.f;
    for (int seg = 0; seg < 16; ++seg) {
        size_t idx = (size_t)(bk * 16 + seg) * DI + d;
        hseg[idx] = h;
        h = segA[idx] * h + segB[idx];
    }
}
__global__ __launch_bounds__(192) void k_cs3(const float* __restrict__ cA,
                                             float* __restrict__ cB,
                                             const float* __restrict__ hseg) {
    int g = blockIdx.x;                 // bk*16 + seg
    int d = threadIdx.x;
    float h = hseg[(size_t)g * DI + d];
    size_t base = (size_t)g * 32 * DI + d;
    for (int cc = 0; cc < 32; ++cc) {
        size_t ix = base + (size_t)cc * DI;
        float a = cA[ix];
        float bb = cB[ix];
        cB[ix] = h;                     // hin for this chunk
        h = a * h + bb;
    }
}

// ---- Kernel 5: phase-3 — scan replay + NON-ATOMIC scatter --------------
template <bool ACCUM>
__global__ __launch_bounds__(192) void k_scan3(const float* __restrict__ xf,
                                               const int* __restrict__ sids,
                                               const float* __restrict__ dtw,
                                               const float* __restrict__ dtb,
                                               const float* __restrict__ alog,
                                               const float* __restrict__ dsv,
                                               const float* __restrict__ hin,
                                               const float* __restrict__ xdblp,
                                               float* __restrict__ y,
                                               int k) {
    __shared__ float xdbl[PCH * 8];
    __shared__ int sid[PCH];
    int bid = blockIdx.x;               // b*NCH + c
    int c = bid & (NCH - 1);
    int b = bid >> 9;
    int t = threadIdx.x;
    size_t gidx = (size_t)((b * KDIR + k) * NCH + c);
    if (t < PCH) sid[t] = sids[k * LLEN + c * PCH + t];
    __syncthreads();
    if (t < 64) {
        int p = t >> 1, half = t & 1;
        reinterpret_cast<float4*>(xdbl)[t] = *reinterpret_cast<const float4*>(
            xdblp + ((size_t)(b * LLEN) + sid[p]) * 32 + k * 8 + half * 4);
    }
    __syncthreads();
    int d = t;
    const float* ubase = xf + (size_t)(b * LLEN) * DI + d;
    float* ybase = y + (size_t)(b * LLEN) * DI + d;
    float uv[PCH];
    #pragma unroll
    for (int p = 0; p < PCH; ++p) uv[p] = ubase[(size_t)sid[p] * DI];
    float yv[PCH];
    if (ACCUM) {
        #pragma unroll
        for (int p = 0; p < PCH; ++p) yv[p] = ybase[(size_t)sid[p] * DI];
    }
    float wr[6];
    #pragma unroll
    for (int r = 0; r < 6; ++r) wr[r] = dtw[(k * DI + d) * 6 + r];
    float bias = dtb[k * DI + d];
    float A = -__expf(alog[k * DI + d]);
    float Dv = dsv[k * DI + d];
    float h = hin[gidx * DI + d];
    const float4* xd4 = reinterpret_cast<const float4*>(xdbl);
    #pragma unroll
    for (int p = 0; p < PCH; ++p) {
        float4 x0 = xd4[p * 2], x1 = xd4[p * 2 + 1];
        float s = bias + wr[0] * x0.x + wr[1] * x0.y + wr[2] * x0.z +
                  wr[3] * x0.w + wr[4] * x1.x + wr[5] * x1.y;
        float delta = (s > 20.f) ? s : __logf(1.f + __expf(s));
        float a = __expf(delta * A);
        float bu = delta * x1.z * uv[p];
        h = a * h + bu;
        float ys = x1.w * h + Dv * uv[p];
        if (ACCUM) ys += yv[p];
        ybase[(size_t)sid[p] * DI] = ys;    // plain store, no atomic
    }
}

// ------------- Kernel 6: GELU + out_proj (192 -> 96) --------------------
__global__ __launch_bounds__(256) void k_out(const float* __restrict__ y,
                                             const float* __restrict__ wo,
                                             float* __restrict__ out) {
    __shared__ float gy[DI * 65];       // [c][l] stride 65 (pad)
    int bid = blockIdx.x;
    int b = bid >> 8;
    int l0 = (bid & 255) << 6;
    int t = threadIdx.x;
    for (int i = 0; i < 48; ++i) {
        int idx = t + i * 256;          // 0..12287
        int l = idx / DI;
        int cc = idx - l * DI;
        float v = y[((size_t)(b * LLEN) + l0 + l) * DI + cc];
        float z = 0.7978845608028654f * (v + 0.044715f * v * v * v);
        float e = __expf(2.f * z);
        float th = 1.f - 2.f * __builtin_amdgcn_rcpf(e + 1.f);
        gy[cc * 65 + l] = 0.5f * v * (1.f + th);
    }
    __syncthreads();
    int lq = t & 15, oh = t >> 4;
    float acc[6][4];
    #pragma unroll
    for (int i = 0; i < 6; ++i)
        #pragma unroll
        for (int e = 0; e < 4; ++e) acc[i][e] = 0.f;
    for (int cc = 0; cc < DI; cc += 4) {
        float4 wv[6];
        #pragma unroll
        for (int i = 0; i < 6; ++i)
            wv[i] = *reinterpret_cast<const float4*>(&wo[(oh * 6 + i) * DI + cc]);
        float g[4][4];                  // [e_l][e_cc]
        #pragma unroll
        for (int el = 0; el < 4; ++el) {
            g[el][0] = gy[(cc + 0) * 65 + lq * 4 + el];
            g[el][1] = gy[(cc + 1) * 65 + lq * 4 + el];
            g[el][2] = gy[(cc + 2) * 65 + lq * 4 + el];
            g[el][3] = gy[(cc + 3) * 65 + lq * 4 + el];
        }
        #pragma unroll
        for (int i = 0; i < 6; ++i)
            #pragma unroll
            for (int el = 0; el < 4; ++el)
                acc[i][el] += wv[i].x * g[el][0] + wv[i].y * g[el][1] +
                              wv[i].z * g[el][2] + wv[i].w * g[el][3];
    }
    #pragma unroll
    for (int i = 0; i < 6; ++i) {
        int o = oh * 6 + i;
        float4 st = make_float4(acc[i][0], acc[i][1], acc[i][2], acc[i][3]);
        *reinterpret_cast<float4*>(&out[((size_t)(b * CIN) + o) * LLEN + l0 + lq * 4]) = st;
    }
}

extern "C" void kernel_launch(void* const* d_in, const int* in_sizes, int n_in,
                              void* d_out, int out_size, void* d_ws, size_t ws_size,
                              hipStream_t stream) {
    const float* x        = (const float*)d_in[0];
    const int*   scan_ids = (const int*)d_in[1];
    const float* in_proj_w = (const float*)d_in[3];
    const float* conv_w    = (const float*)d_in[4];
    const float* conv_b    = (const float*)d_in[5];
    const float* xpw       = (const float*)d_in[6];
    const float* dtw       = (const float*)d_in[7];
    const float* dtb       = (const float*)d_in[8];
    const float* alog      = (const float*)d_in[9];
    const float* dsv       = (const float*)d_in[10];
    const float* wo        = (const float*)d_in[11];
    float* out = (float*)d_out;

    float* ws = (float*)d_ws;
    const size_t NBL  = (size_t)BATCH * LLEN * DI;        // 12.58M floats
    const size_t NCK  = (size_t)BATCH * KDIR * NCH * DI;  // 1.57M floats
    const size_t NXD  = (size_t)BATCH * LLEN * 32;        // 2.10M floats
    const size_t NSG  = (size_t)BATCH * KDIR * 16 * DI;   // 49152 floats
    float* t0    = ws;             // in_proj out; later reused as y
    float* xf    = t0 + NBL;
    float* xdblp = xf + NBL;
    float* cA    = xdblp + NXD;
    float* cB    = cA + NCK;       // becomes hin after k_cs3
    float* segA  = cB + NCK;
    float* segB  = segA + NSG;
    float* hseg  = segB + NSG;
    float* y     = t0;
    // bf16 staging aliases (dead before their hosts are written):
    // Xb (B*L*96 bf16 = 12.58 MB) over cA..cB (12.58 MB);  Wb over segA.
    unsigned short* Xb = reinterpret_cast<unsigned short*>(cA);
    unsigned*       Wb = reinterpret_cast<unsigned*>(segA);

    k_cvtw<<<36, 256, 0, stream>>>(in_proj_w, Wb);
    k_cvt<<<256, 256, 0, stream>>>(x, Xb);
    k_inproj<<<BATCH * 256, 256, 0, stream>>>(Xb, (const unsigned short*)Wb, t0);
    k_dwconv<<<BATCH * HH * 16, 192, 0, stream>>>(t0, conv_w, conv_b, xf);
    k_proj<<<(BATCH * LLEN) / 32, 256, 0, stream>>>(xf, xpw, xdblp);
    k_scan1<<<BATCH * KDIR * NCH, 192, 0, stream>>>(xf, scan_ids, xdblp, dtw, dtb,
                                                    alog, cA, cB);
    k_cs1<<<BATCH * KDIR * 16, 192, 0, stream>>>(cA, cB, segA, segB);
    k_cs2<<<BATCH * KDIR, 192, 0, stream>>>(segA, segB, hseg);
    k_cs3<<<BATCH * KDIR * 16, 192, 0, stream>>>(cA, cB, hseg);
    k_scan3<false><<<BATCH * NCH, 192, 0, stream>>>(xf, scan_ids, dtw, dtb,
                                                    alog, dsv, cB, xdblp, y, 0);
    for (int k = 1; k < KDIR; ++k)
        k_scan3<true><<<BATCH * NCH, 192, 0, stream>>>(xf, scan_ids, dtw, dtb,
                                                       alog, dsv, cB, xdblp, y, k);
    k_out<<<BATCH * 256, 256, 0, stream>>>(y, wo, out);
}